// Round 6
// baseline (108.544 us; speedup 1.0000x reference)
//
#include <hip/hip_runtime.h>

constexpr int IN_F  = 256;
constexpr int OUT_F = 512;
constexpr int BATCH = 2048;

// pack[(o,i)] = {p0,p1,p2,p3 | q1,q2,q3,w} : one aligned 32B record so the
// hot loop issues uniform scalar loads (s_load_dwordx8) per element.
__global__ __launch_bounds__(256) void prep_pack8_kernel(
    const float* __restrict__ p, const float* __restrict__ q,
    const float* __restrict__ w, float4* __restrict__ pk, int n) {
    int t = blockIdx.x * 256 + threadIdx.x;
    if (t < n) {
        pk[2 * t]     = make_float4(p[4 * t], p[4 * t + 1], p[4 * t + 2], p[4 * t + 3]);
        pk[2 * t + 1] = make_float4(q[3 * t], q[3 * t + 1], q[3 * t + 2], w[t]);
    }
}

// x3[b,i] = RN(x^3) computed in f64 ONCE per (b,i) (was recomputed in all 64
// o-blocks = 64x redundant f64 VALU in the hot loop).
__global__ __launch_bounds__(256) void prep_x3_kernel(
    const float* __restrict__ x, float* __restrict__ x3, int n) {
    int t = blockIdx.x * 256 + threadIdx.x;
    if (t < n) {
        const double xd = (double)x[t];
        x3[t] = (float)(xd * xd * xd);   // RN(x^3) == powf(x,3)
    }
}

// Block = 64 batches (lanes) x 8 outputs. Waves split the i-dimension; each
// wave computes all 8 outputs. 8KB LDS reduction combines the 4 per-wave
// partials. Grid = 2048 blocks = 8 blocks/CU.
//
// NUMERICS (bit-exact vs np reference -- DO NOT REORDER, verified R3-R5,
// absmax 768 vs threshold 5.7e5):
//   x^2 = RN(x*x); x^3 = RN(x^3) via f64 (now from table); S = fmaf chain
//   ascending p starting from RN(c1*x); Q' = (1+S)+1e-6 as two separate
//   adds; division via rcp (relative-error-only).
//
// MODE: 2 = packed coeffs + x3 table; 1 = packed coeffs, in-loop f64 x3
// (R5-identical); 0 = raw arrays fallback.
template <int MODE>
__global__ __launch_bounds__(256, 8) void kan_kernel(
    const float*  __restrict__ x,
    const float4* __restrict__ Pc,    // (O, I) of {p0,p1,p2,p3}
    const float*  __restrict__ Qc,    // (O, I, 3) raw (MODE 0)
    const float4* __restrict__ PK,    // (O, I) of 2x float4 (MODE >= 1)
    const float*  __restrict__ X3,    // (B, I) RN(x^3) table (MODE 2)
    const float*  __restrict__ W,     // (O, I) raw (MODE 0)
    const float*  __restrict__ bias,  // (O)
    float* __restrict__ out)          // (B, O)
{
#pragma clang fp contract(off)       // protect the explicit add sequence
    const int lane  = threadIdx.x & 63;
    const int wave  = __builtin_amdgcn_readfirstlane(threadIdx.x >> 6);
    const int b     = blockIdx.x * 64 + lane;
    const int o0    = blockIdx.y * 8;
    const int ibase = wave * 64;      // this wave's i-slice

    float acc[8] = {0.f, 0.f, 0.f, 0.f, 0.f, 0.f, 0.f, 0.f};
    const float* xrow  = x + (size_t)b * IN_F + ibase;
    const float* x3row = (MODE == 2) ? (X3 + (size_t)b * IN_F + ibase) : nullptr;

    for (int ic = 0; ic < 64; ic += 4) {
        const float4 xq = *reinterpret_cast<const float4*>(xrow + ic);
        float x1[4] = {xq.x, xq.y, xq.z, xq.w};
        float x2[4], x3[4];
        if (MODE == 2) {
            const float4 x3q = *reinterpret_cast<const float4*>(x3row + ic);
            x3[0] = x3q.x; x3[1] = x3q.y; x3[2] = x3q.z; x3[3] = x3q.w;
#pragma unroll
            for (int j = 0; j < 4; ++j) x2[j] = x1[j] * x1[j];  // RN(x^2)
        } else {
#pragma unroll
            for (int j = 0; j < 4; ++j) {
                x2[j] = x1[j] * x1[j];
                const double xd = (double)x1[j];
                x3[j] = (float)(xd * xd * xd);
            }
        }
        const int rowi = ibase + ic;
#pragma unroll
        for (int oo = 0; oo < 8; ++oo) {
            const int rowbase = (o0 + oo) * IN_F + rowi;
#pragma unroll
            for (int j = 0; j < 4; ++j) {          // 4 contiguous 32B records
                float p0, p1, p2, p3, q1, q2, q3, wv;
                if (MODE >= 1) {
                    const float4 pa = PK[2 * (rowbase + j)];
                    const float4 pb = PK[2 * (rowbase + j) + 1];
                    p0 = pa.x; p1 = pa.y; p2 = pa.z; p3 = pa.w;
                    q1 = pb.x; q2 = pb.y; q3 = pb.z; wv = pb.w;
                } else {
                    const float4 pc = Pc[rowbase + j];
                    const float* qp = Qc + (size_t)(rowbase + j) * 3;
                    p0 = pc.x; p1 = pc.y; p2 = pc.z; p3 = pc.w;
                    q1 = qp[0]; q2 = qp[1]; q3 = qp[2];
                    wv = W[rowbase + j];
                }
                // ---- S_Q : einsum fmaf chain, accum starts at 0 ----
                float t = q1 * x1[j];              // == fma(q1,x1,0)
                t = fmaf(q2, x2[j], t);
                t = fmaf(q3, x3[j], t);
                float Qv = 1.0f + t;               // Sterbenz-exact near pole
                float Qp = Qv + 1e-6f;
                // ---- S_P : same einsum chain ----
                float s = fmaf(p1, x1[j], p0);
                s = fmaf(p2, x2[j], s);
                s = fmaf(p3, x3[j], s);
                const float r = __builtin_amdgcn_rcpf(Qp);
                acc[oo] = fmaf(s, r, acc[oo]);       // rational term
                acc[oo] = fmaf(wv, x1[j], acc[oo]);  // fused base matmul
            }
        }
    }

    // ---- cross-wave reduction: red[wave][lane][o] ----
    __shared__ float red[4 * 64 * 8];
    float4* dst = reinterpret_cast<float4*>(&red[(wave * 64 + lane) * 8]);
    dst[0] = make_float4(acc[0], acc[1], acc[2], acc[3]);
    dst[1] = make_float4(acc[4], acc[5], acc[6], acc[7]);
    __syncthreads();

#pragma unroll
    for (int k = 0; k < 2; ++k) {
        const int idx = threadIdx.x + k * 256;     // idx = bb*8 + o
        float s = red[idx] + red[512 + idx];       // wave order 0,1,2,3
        s = s + red[1024 + idx];
        s = s + red[1536 + idx];
        const int bb = idx >> 3, o = idx & 7;
        s = s + bias[o0 + o];
        out[(size_t)(blockIdx.x * 64 + bb) * OUT_F + o0 + o] = s;
    }
}

extern "C" void kernel_launch(void* const* d_in, const int* in_sizes, int n_in,
                              void* d_out, int out_size, void* d_ws, size_t ws_size,
                              hipStream_t stream) {
    const float* x    = (const float*)d_in[0];
    const float* Pc   = (const float*)d_in[1];
    const float* Qc   = (const float*)d_in[2];
    const float* W    = (const float*)d_in[3];
    const float* bias = (const float*)d_in[4];
    float* out = (float*)d_out;

    const int n  = OUT_F * IN_F;          // 131072 (o,i) records
    const int nx = BATCH * IN_F;          // 524288 (b,i) x-powers
    const size_t pk_bytes = (size_t)n * 32;
    dim3 grid(BATCH / 64, OUT_F / 8);     // 2048 blocks = 8/CU

    if (ws_size >= pk_bytes + (size_t)nx * sizeof(float)) {
        float4* pk = (float4*)d_ws;
        float*  x3 = (float*)((char*)d_ws + pk_bytes);
        prep_pack8_kernel<<<(n + 255) / 256, 256, 0, stream>>>(Pc, Qc, W, pk, n);
        prep_x3_kernel<<<(nx + 255) / 256, 256, 0, stream>>>(x, x3, nx);
        kan_kernel<2><<<grid, 256, 0, stream>>>(
            x, (const float4*)Pc, Qc, pk, x3, W, bias, out);
    } else if (ws_size >= pk_bytes) {
        float4* pk = (float4*)d_ws;
        prep_pack8_kernel<<<(n + 255) / 256, 256, 0, stream>>>(Pc, Qc, W, pk, n);
        kan_kernel<1><<<grid, 256, 0, stream>>>(
            x, (const float4*)Pc, Qc, pk, nullptr, W, bias, out);
    } else {
        kan_kernel<0><<<grid, 256, 0, stream>>>(
            x, (const float4*)Pc, Qc, nullptr, nullptr, W, bias, out);
    }
}